// Round 3
// baseline (113.853 us; speedup 1.0000x reference)
//
#include <hip/hip_runtime.h>

#define HW    36864
#define PXT   144    // px per block: 36864 / 256 blocks
#define RST   136    // rel_s row stride (u16): 128 + 8 pad
#define PST   136    // prob_t px stride (u16): 272 B

typedef unsigned short u16;
typedef unsigned int   u32;
typedef __attribute__((ext_vector_type(8))) short bf16x8;
typedef __attribute__((ext_vector_type(4))) float f32x4;

__device__ __forceinline__ float bf2f(u32 u) {
    union { u32 i; float f; } c; c.i = u << 16; return c.f;
}
__device__ __forceinline__ u16 f2bf(float f) {
    union { float f; u32 i; } c; c.f = f;
    u32 r = (c.i + 0x7fffu + ((c.i >> 16) & 1u)) >> 16;  // RNE
    return (u16)r;
}
__device__ __forceinline__ u32 pack2(float a, float b) {
    return (u32)f2bf(a) | ((u32)f2bf(b) << 16);
}
__device__ __forceinline__ float sigf(float x) { return 1.0f / (1.0f + __expf(-x)); }

// Block-wide dtype self-detect (criterion empirically validated). Includes a
// barrier; call before any LDS use, all threads participating.
__device__ __forceinline__ bool is_bf16_blk(const void* ml, int tid) {
    int pred = 0;
    if (tid < 128) {
        u16 v = ((const u16*)ml)[tid];
        u32 e = (v >> 7) & 0xffu;
        pred = ((v & 0x7fffu) == 0 || (e >= 90u && e <= 140u)) ? 1 : 0;
    }
    int cnt = __syncthreads_count(pred);
    return cnt >= 100;
}

// ---------------------------------------------------------------------------
// k_rel: relN[n][m] = relu(ov(n,m) - ov(m,n)) as bf16, row-major.
// grid 128 (n), block 256. Class term via cooperative per-class dot table
// (coalesced loads + shfl_xor reduce), then per-m lookup + 64-wide pos loop.
// ---------------------------------------------------------------------------
__global__ __launch_bounds__(256) void k_rel(
    const void* __restrict__ ml,   const void* __restrict__ bbox,
    const void* __restrict__ WU,   const void* __restrict__ WV,
    const void* __restrict__ Wpos, const void* __restrict__ WP,
    const int* __restrict__ cls,   u16* __restrict__ relN)
{
    const int tid = threadIdx.x;
    const bool bf = is_bf16_blk(ml, tid);
    const int n = blockIdx.x;

    __shared__ float u_s[128], v_s[128], wpos_s[256], wpp_s[64], bbn_s[4];
    __shared__ float d1_s[80], d2_s[80];

    const int cn = cls[n] - 1;
    if (bf) {
        if (tid < 128) {
            float wp = bf2f(((const u16*)WP)[tid]);
            u_s[tid] = fmaxf(bf2f(((const u16*)WU)[cn * 128 + tid]), 0.f) * wp;
            v_s[tid] = fmaxf(bf2f(((const u16*)WV)[cn * 128 + tid]), 0.f) * wp;
        }
        wpos_s[tid] = bf2f(((const u16*)Wpos)[tid]);
        if (tid < 64) wpp_s[tid] = bf2f(((const u16*)WP)[128 + tid]);
        if (tid < 4)  bbn_s[tid] = bf2f(((const u16*)bbox)[n * 4 + tid]);
    } else {
        if (tid < 128) {
            float wp = ((const float*)WP)[tid];
            u_s[tid] = fmaxf(((const float*)WU)[cn * 128 + tid], 0.f) * wp;
            v_s[tid] = fmaxf(((const float*)WV)[cn * 128 + tid], 0.f) * wp;
        }
        wpos_s[tid] = ((const float*)Wpos)[tid];
        if (tid < 64) wpp_s[tid] = ((const float*)WP)[128 + tid];
        if (tid < 4)  bbn_s[tid] = ((const float*)bbox)[n * 4 + tid];
    }
    __syncthreads();

    {
        const int wv_ = tid >> 6, lane = tid & 63;
        const float ua = u_s[lane], ub = u_s[64 + lane];
        const float va = v_s[lane], vb = v_s[64 + lane];
        for (int a = wv_; a < 80; a += 4) {
            float x0, x1, y0, y1;
            if (bf) {
                x0 = bf2f(((const u16*)WV)[a * 128 + lane]);
                x1 = bf2f(((const u16*)WV)[a * 128 + 64 + lane]);
                y0 = bf2f(((const u16*)WU)[a * 128 + lane]);
                y1 = bf2f(((const u16*)WU)[a * 128 + 64 + lane]);
            } else {
                x0 = ((const float*)WV)[a * 128 + lane];
                x1 = ((const float*)WV)[a * 128 + 64 + lane];
                y0 = ((const float*)WU)[a * 128 + lane];
                y1 = ((const float*)WU)[a * 128 + 64 + lane];
            }
            float p1 = ua * fmaxf(x0, 0.f) + ub * fmaxf(x1, 0.f);
            float p2 = va * fmaxf(y0, 0.f) + vb * fmaxf(y1, 0.f);
            #pragma unroll
            for (int o = 32; o; o >>= 1) {
                p1 += __shfl_xor(p1, o);
                p2 += __shfl_xor(p2, o);
            }
            if (lane == 0) { d1_s[a] = p1; d2_s[a] = p2; }
        }
    }
    __syncthreads();

    if (tid >= 128) return;
    const int m = tid;
    const int cm = cls[m] - 1;
    float s1 = d1_s[cm];
    float s2 = d2_s[cm];

    const float xmn = bbn_s[0], ymn = bbn_s[1], xMn = bbn_s[2], yMn = bbn_s[3];
    const float wn = xMn - xmn, hn = yMn - ymn;
    const float xcn = 0.5f * (xmn + xMn), ycn = 0.5f * (ymn + yMn);
    float xmm, ymm, xMm, yMm;
    if (bf) {
        xmm = bf2f(((const u16*)bbox)[m * 4 + 0]); ymm = bf2f(((const u16*)bbox)[m * 4 + 1]);
        xMm = bf2f(((const u16*)bbox)[m * 4 + 2]); yMm = bf2f(((const u16*)bbox)[m * 4 + 3]);
    } else {
        xmm = ((const float*)bbox)[m * 4 + 0]; ymm = ((const float*)bbox)[m * 4 + 1];
        xMm = ((const float*)bbox)[m * 4 + 2]; yMm = ((const float*)bbox)[m * 4 + 3];
    }
    const float wm = xMm - xmm, hm = yMm - ymm;
    const float xcm = 0.5f * (xmm + xMm), ycm = 0.5f * (ymm + yMm);

    const float p0 = -(xcn - xcm) / wn, p1 = -(ycn - ycm) / hn;
    const float p2 = __logf(wm / wn),   p3 = __logf(hm / hn);
    const float q0 = -(xcm - xcn) / wm, q1 = -(ycm - ycn) / hm;
    const float q2 = __logf(wn / wm),   q3 = __logf(hn / hm);

    #pragma unroll 8
    for (int d = 0; d < 64; ++d) {
        float w0 = wpos_s[d], w1 = wpos_s[64 + d], w2 = wpos_s[128 + d], w3 = wpos_s[192 + d];
        float wp = wpp_s[d];
        float t1 = p0 * w0 + p1 * w1 + p2 * w2 + p3 * w3;
        float t2 = q0 * w0 + q1 * w1 + q2 * w2 + q3 * w3;
        s1 += fmaxf(t1, 0.f) * wp;
        s2 += fmaxf(t2, 0.f) * wp;
    }

    float r = fmaxf(sigf(s1) - sigf(s2), 0.f);
    relN[n * 128 + m] = f2bf(r);
}

// ---------------------------------------------------------------------------
// k_main: out[n,px] = ml - ml*prob*(sum_m rel[n,m]*prob[m,px]) via MFMA.
// grid 256 x 512 threads (8 waves). n=128 full, px tile 144; wave w owns
// n-tile [16w,16w+16), all 9 px-tiles. prob stored TRANSPOSED prob_t[px][k]
// so a B-fragment is ONE ds_read_b128.
// Pipeline (T14 split): stage k-half0 -> barrier -> ISSUE half1 global loads
// into regs -> MFMA over half0 (HBM latency hides under ~18 MFMAs/wave +
// 16 waves/CU TLP) -> sigmoid+ds_write half1 -> barrier -> MFMA half1.
// The two k-halves are disjoint LDS regions (elems 0..63 vs 64..127 of each
// px row), so no double buffer: LDS stays 74 KB -> 2 blocks/CU.
// ---------------------------------------------------------------------------
__global__ __launch_bounds__(512) void k_main(
    const void* __restrict__ mlv, const u16* __restrict__ relN,
    void* __restrict__ outv)
{
    const int tid = threadIdx.x;
    const bool bf = is_bf16_blk(mlv, tid);

    __shared__ u16 rel_s[128 * RST];    // 34816 B
    __shared__ u16 prob_t[PXT * PST];   // 39168 B  (total 74 KB)

    const int px0  = blockIdx.x * PXT;
    const int lane = tid & 63;
    const int col  = lane & 15;
    const int quad = lane >> 4;
    const int n0   = (tid >> 6) * 16;   // wave's n-tile base

    // stage rel: re-stride 128x128 -> 128xRST (coalesced b128 both sides)
    for (int idx = tid; idx < 2048; idx += 512) {
        int r = idx >> 4, c = idx & 15;
        uint4 v = ((const uint4*)relN)[idx];
        *(uint4*)(rel_s + r * RST + c * 8) = v;
    }

    // ---- stage half0: k in [0,64). unit u -> (px = u%PXT, kg = u/PXT),
    // consecutive lanes = consecutive px at same k -> coalesced reads;
    // b128 LDS write per unit.
    #pragma unroll
    for (int i = 0; i < 3; ++i) {
        int u = tid + i * 512;
        if (u < PXT * 8) {
            int px = u % PXT, kg = u / PXT;
            size_t gbase = (size_t)(kg * 8) * HW + px0 + px;
            float f[8];
            if (bf) {
                #pragma unroll
                for (int j = 0; j < 8; ++j)
                    f[j] = bf2f((u32)((const u16*)mlv)[gbase + (size_t)j * HW]);
            } else {
                #pragma unroll
                for (int j = 0; j < 8; ++j)
                    f[j] = ((const float*)mlv)[gbase + (size_t)j * HW];
            }
            uint4 o;
            o.x = pack2(sigf(f[0]), sigf(f[1]));
            o.y = pack2(sigf(f[2]), sigf(f[3]));
            o.z = pack2(sigf(f[4]), sigf(f[5]));
            o.w = pack2(sigf(f[6]), sigf(f[7]));
            *(uint4*)(prob_t + px * PST + kg * 8) = o;
        }
    }
    __syncthreads();   // rel_s + prob_t half0 ready

    // ---- issue half1 global loads into registers (k in [64,128))
    float hf[3][8];
    #pragma unroll
    for (int i = 0; i < 3; ++i) {
        int u = tid + i * 512;
        if (u < PXT * 8) {
            int px = u % PXT, kg = 8 + u / PXT;
            size_t gbase = (size_t)(kg * 8) * HW + px0 + px;
            if (bf) {
                #pragma unroll
                for (int j = 0; j < 8; ++j)
                    hf[i][j] = bf2f((u32)((const u16*)mlv)[gbase + (size_t)j * HW]);
            } else {
                #pragma unroll
                for (int j = 0; j < 8; ++j)
                    hf[i][j] = ((const float*)mlv)[gbase + (size_t)j * HW];
            }
        }
    }

    f32x4 acc[9];
    #pragma unroll
    for (int t = 0; t < 9; ++t) acc[t] = (f32x4){0.f, 0.f, 0.f, 0.f};

    // ---- MFMA over half0 (k 0..63) while half1 loads are in flight
    #pragma unroll
    for (int ks = 0; ks < 2; ++ks) {
        const int k0 = ks * 32 + quad * 8;
        bf16x8 a = *(const bf16x8*)(rel_s + (n0 + col) * RST + k0);
        #pragma unroll
        for (int t = 0; t < 9; ++t) {
            bf16x8 b = *(const bf16x8*)(prob_t + (t * 16 + col) * PST + k0);
            acc[t] = __builtin_amdgcn_mfma_f32_16x16x32_bf16(a, b, acc[t], 0, 0, 0);
        }
    }

    // ---- sigmoid + write half1 into its (disjoint) LDS region
    #pragma unroll
    for (int i = 0; i < 3; ++i) {
        int u = tid + i * 512;
        if (u < PXT * 8) {
            int px = u % PXT, kg = 8 + u / PXT;
            uint4 o;
            o.x = pack2(sigf(hf[i][0]), sigf(hf[i][1]));
            o.y = pack2(sigf(hf[i][2]), sigf(hf[i][3]));
            o.z = pack2(sigf(hf[i][4]), sigf(hf[i][5]));
            o.w = pack2(sigf(hf[i][6]), sigf(hf[i][7]));
            *(uint4*)(prob_t + px * PST + kg * 8) = o;
        }
    }
    __syncthreads();   // half1 ready

    // ---- MFMA over half1 (k 64..127)
    #pragma unroll
    for (int ks = 2; ks < 4; ++ks) {
        const int k0 = ks * 32 + quad * 8;
        bf16x8 a = *(const bf16x8*)(rel_s + (n0 + col) * RST + k0);
        #pragma unroll
        for (int t = 0; t < 9; ++t) {
            bf16x8 b = *(const bf16x8*)(prob_t + (t * 16 + col) * PST + k0);
            acc[t] = __builtin_amdgcn_mfma_f32_16x16x32_bf16(a, b, acc[t], 0, 0, 0);
        }
    }

    // epilogue: C/D layout col=lane&15, row=quad*4+reg; ml re-read is L2-hot
    #pragma unroll
    for (int t = 0; t < 9; ++t) {
        const int px = px0 + t * 16 + col;
        #pragma unroll
        for (int r = 0; r < 4; ++r) {
            size_t off = (size_t)(n0 + quad * 4 + r) * HW + px;
            if (bf) {
                float mlvv = bf2f((u32)((const u16*)mlv)[off]);
                float pr = sigf(mlvv);
                ((u16*)outv)[off] = f2bf(mlvv - mlvv * pr * acc[t][r]);
            } else {
                float mlvv = ((const float*)mlv)[off];
                float pr = sigf(mlvv);
                ((float*)outv)[off] = mlvv - mlvv * pr * acc[t][r];
            }
        }
    }
}

extern "C" void kernel_launch(void* const* d_in, const int* in_sizes, int n_in,
                              void* d_out, int out_size, void* d_ws, size_t ws_size,
                              hipStream_t stream) {
    const void* ml   = d_in[0];
    const void* bbox = d_in[1];
    const void* WU   = d_in[2];
    const void* WV   = d_in[3];
    const void* Wpos = d_in[4];
    const void* WP   = d_in[5];
    const int*  cls  = (const int*)d_in[6];

    u16* relN = (u16*)d_ws;   // 32 KB, [n][m] row-major bf16

    k_rel<<<dim3(128), dim3(256), 0, stream>>>(ml, bbox, WU, WV, Wpos, WP, cls, relN);
    k_main<<<dim3(256), dim3(512), 0, stream>>>(ml, relN, d_out);
}

// Round 4
// 106.903 us; speedup vs baseline: 1.0650x; 1.0650x over previous
//
#include <hip/hip_runtime.h>

#define HW    36864
#define PX    144    // px per block: 36864 / 256 blocks
#define RST   136    // rel_s row stride (elements): 128 + 8 pad -> b128 reads 2-way only

typedef unsigned short u16;
typedef unsigned int   u32;
typedef __attribute__((ext_vector_type(8))) short bf16x8;
typedef __attribute__((ext_vector_type(4))) float f32x4;

__device__ __forceinline__ float bf2f(u32 u) {
    union { u32 i; float f; } c; c.i = u << 16; return c.f;
}
__device__ __forceinline__ u16 f2bf(float f) {
    union { float f; u32 i; } c; c.f = f;
    u32 r = (c.i + 0x7fffu + ((c.i >> 16) & 1u)) >> 16;  // RNE
    return (u16)r;
}
__device__ __forceinline__ u32 pack2(float a, float b) {
    return (u32)f2bf(a) | ((u32)f2bf(b) << 16);
}
__device__ __forceinline__ float sigf(float x) { return 1.0f / (1.0f + __expf(-x)); }

__device__ __forceinline__ void unpack8(uint4 v, float* o) {
    o[0] = bf2f(v.x & 0xffffu); o[1] = bf2f(v.x >> 16);
    o[2] = bf2f(v.y & 0xffffu); o[3] = bf2f(v.y >> 16);
    o[4] = bf2f(v.z & 0xffffu); o[5] = bf2f(v.z >> 16);
    o[6] = bf2f(v.w & 0xffffu); o[7] = bf2f(v.w >> 16);
}

template<int BF16>
__device__ __forceinline__ float ld1(const void* p, int idx) {
    return BF16 ? bf2f((u32)((const u16*)p)[idx]) : ((const float*)p)[idx];
}

// Block-wide dtype self-detect (identical criterion to the round-2 k_detect,
// which empirically selected the passing path). Includes a barrier; call
// before any LDS use, all threads. Returns true if THIS variant is wrong.
template<int BF16>
__device__ __forceinline__ bool wrong_dtype(const void* ml, int tid) {
    int pred = 0;
    if (tid < 128) {
        u16 v = ((const u16*)ml)[tid];
        u32 e = (v >> 7) & 0xffu;
        pred = ((v & 0x7fffu) == 0 || (e >= 90u && e <= 140u)) ? 1 : 0;
    }
    int cnt = __syncthreads_count(pred);
    return (cnt >= 100) != (BF16 != 0);
}

// ---------------------------------------------------------------------------
// k_rel: relN[n][m] = relu(ov(n,m) - ov(m,n)) as bf16, row-major (m contig).
// grid 128 (n), block 128 (m). Each thread computes BOTH directions using
// block-shared u_s = relu(WU[cn])*WP and v_s = relu(WV[cn])*WP.
// ---------------------------------------------------------------------------
template<int BF16>
__global__ __launch_bounds__(128) void k_rel(
    const void* __restrict__ ml,   const void* __restrict__ bbox,
    const void* __restrict__ WU,   const void* __restrict__ WV,
    const void* __restrict__ Wpos, const void* __restrict__ WP,
    const int* __restrict__ cls,   u16* __restrict__ relN)
{
    const int n = blockIdx.x, m = threadIdx.x;
    if (wrong_dtype<BF16>(ml, m)) return;

    __shared__ float u_s[128], v_s[128], wpos_s[256], wpp_s[64], bbn_s[4];

    const int cn = cls[n] - 1;
    {
        float wp = ld1<BF16>(WP, m);
        u_s[m] = fmaxf(ld1<BF16>(WU, cn * 128 + m), 0.f) * wp;
        v_s[m] = fmaxf(ld1<BF16>(WV, cn * 128 + m), 0.f) * wp;
    }
    wpos_s[m]       = ld1<BF16>(Wpos, m);
    wpos_s[128 + m] = ld1<BF16>(Wpos, 128 + m);
    if (m < 64) wpp_s[m] = ld1<BF16>(WP, 128 + m);
    if (m < 4)  bbn_s[m] = ld1<BF16>(bbox, n * 4 + m);
    __syncthreads();

    // class term, both directions
    const int cm = cls[m] - 1;
    float s1 = 0.f, s2 = 0.f;
    #pragma unroll 8
    for (int c = 0; c < 128; ++c) {
        float wv = ld1<BF16>(WV, cm * 128 + c);
        float wu = ld1<BF16>(WU, cm * 128 + c);
        s1 += u_s[c] * fmaxf(wv, 0.f);
        s2 += v_s[c] * fmaxf(wu, 0.f);
    }

    // position term, both directions
    const float xmn = bbn_s[0], ymn = bbn_s[1], xMn = bbn_s[2], yMn = bbn_s[3];
    const float wn = xMn - xmn, hn = yMn - ymn;
    const float xcn = 0.5f * (xmn + xMn), ycn = 0.5f * (ymn + yMn);
    const float xmm = ld1<BF16>(bbox, m * 4 + 0), ymm = ld1<BF16>(bbox, m * 4 + 1);
    const float xMm = ld1<BF16>(bbox, m * 4 + 2), yMm = ld1<BF16>(bbox, m * 4 + 3);
    const float wm = xMm - xmm, hm = yMm - ymm;
    const float xcm = 0.5f * (xmm + xMm), ycm = 0.5f * (ymm + yMm);

    const float p0 = -(xcn - xcm) / wn, p1 = -(ycn - ycm) / hn;
    const float p2 = __logf(wm / wn),   p3 = __logf(hm / hn);
    const float q0 = -(xcm - xcn) / wm, q1 = -(ycm - ycn) / hm;
    const float q2 = __logf(wn / wm),   q3 = __logf(hn / hm);

    #pragma unroll 8
    for (int d = 0; d < 64; ++d) {
        float w0 = wpos_s[d], w1 = wpos_s[64 + d], w2 = wpos_s[128 + d], w3 = wpos_s[192 + d];
        float wp = wpp_s[d];
        float t1 = p0 * w0 + p1 * w1 + p2 * w2 + p3 * w3;
        float t2 = q0 * w0 + q1 * w1 + q2 * w2 + q3 * w3;
        s1 += fmaxf(t1, 0.f) * wp;
        s2 += fmaxf(t2, 0.f) * wp;
    }

    float r = fmaxf(sigf(s1) - sigf(s2), 0.f);
    relN[n * 128 + m] = f2bf(r);
}

// ---------------------------------------------------------------------------
// k_main: out[n,px] = ml - ml*prob*(sum_m rel[n,m]*prob[m,px])  via MFMA.
// grid 256 x 256 threads (4 waves). Per block: n=128 full, px tile = 144.
// Wave w: n-tiles {32w, 32w+16}, 9 px-tiles of 16. K=128 in two LDS halves.
// rel_s: [n][RST] bf16 (A operand, k contiguous, b128). prob_s: [64][144]
// bf16 (B operand via 8x ds_read_u16, lanes consecutive px -> conflict-free).
// ---------------------------------------------------------------------------
template<int BF16>
__global__ __launch_bounds__(256) void k_main(
    const void* __restrict__ mlv, const u16* __restrict__ relN,
    void* __restrict__ outv)
{
    const int tid = threadIdx.x;
    if (wrong_dtype<BF16>(mlv, tid)) return;

    __shared__ u16 rel_s[128 * RST];   // 34816 B
    __shared__ u16 prob_s[64 * PX];    // 18432 B   (total 52 KB)

    const int px0 = blockIdx.x * PX;
    const int w    = tid >> 6;
    const int lane = tid & 63;
    const int col  = lane & 15;
    const int quad = lane >> 4;
    const int n0   = w * 32;

    // stage rel: re-stride 128x128 -> 128xRST (coalesced b128 both sides)
    for (int idx = tid; idx < 2048; idx += 256) {
        int r = idx >> 4, c = idx & 15;
        uint4 v = ((const uint4*)relN)[idx];
        *(uint4*)(rel_s + r * RST + c * 8) = v;
    }

    f32x4 acc[2][9];
    #pragma unroll
    for (int i = 0; i < 2; ++i)
        #pragma unroll
        for (int t = 0; t < 9; ++t) acc[i][t] = (f32x4){0.f, 0.f, 0.f, 0.f};

    for (int h = 0; h < 2; ++h) {
        __syncthreads();   // rel copy done (h=0) / previous-half readers done (h=1)
        // stage prob_s = sigmoid(ml[h*64 .. h*64+63][px0 .. px0+143]) as bf16
        for (int idx = tid; idx < 1152; idx += 256) {
            int r = idx / 18, c = idx - r * 18;
            size_t base = (size_t)(h * 64 + r) * HW + px0 + c * 8;
            float f[8];
            if (BF16) {
                uint4 v = *(const uint4*)((const u16*)mlv + base);
                unpack8(v, f);
            } else {
                float4 v0 = *(const float4*)((const float*)mlv + base);
                float4 v1 = *(const float4*)((const float*)mlv + base + 4);
                f[0] = v0.x; f[1] = v0.y; f[2] = v0.z; f[3] = v0.w;
                f[4] = v1.x; f[5] = v1.y; f[6] = v1.z; f[7] = v1.w;
            }
            uint4 o;
            o.x = pack2(sigf(f[0]), sigf(f[1]));
            o.y = pack2(sigf(f[2]), sigf(f[3]));
            o.z = pack2(sigf(f[4]), sigf(f[5]));
            o.w = pack2(sigf(f[6]), sigf(f[7]));
            *(uint4*)(prob_s + r * PX + c * 8) = o;
        }
        __syncthreads();

        #pragma unroll
        for (int ksl = 0; ksl < 2; ++ksl) {
            const int k0 = h * 64 + ksl * 32 + quad * 8;   // global k of this lane's 8
            bf16x8 a0 = *(const bf16x8*)(rel_s + (n0 + col) * RST + k0);
            bf16x8 a1 = *(const bf16x8*)(rel_s + (n0 + 16 + col) * RST + k0);
            const u16* bbase = prob_s + (ksl * 32 + quad * 8) * PX + col;
            #pragma unroll
            for (int t = 0; t < 9; ++t) {
                const u16* bp = bbase + t * 16;
                bf16x8 bfrag;
                #pragma unroll
                for (int j = 0; j < 8; ++j) bfrag[j] = (short)bp[j * PX];
                acc[0][t] = __builtin_amdgcn_mfma_f32_16x16x32_bf16(a0, bfrag, acc[0][t], 0, 0, 0);
                acc[1][t] = __builtin_amdgcn_mfma_f32_16x16x32_bf16(a1, bfrag, acc[1][t], 0, 0, 0);
            }
        }
    }

    // epilogue: C/D layout col=lane&15, row=quad*4+reg
    #pragma unroll
    for (int i = 0; i < 2; ++i) {
        #pragma unroll
        for (int t = 0; t < 9; ++t) {
            const int nb = n0 + i * 16 + quad * 4;
            const int px = px0 + t * 16 + col;
            #pragma unroll
            for (int r = 0; r < 4; ++r) {
                size_t off = (size_t)(nb + r) * HW + px;
                float mlvv = BF16 ? bf2f((u32)((const u16*)mlv)[off])
                                  : ((const float*)mlv)[off];
                float pr = sigf(mlvv);
                float o  = mlvv - mlvv * pr * acc[i][t][r];
                if (BF16) ((u16*)outv)[off] = f2bf(o);
                else      ((float*)outv)[off] = o;
            }
        }
    }
}

extern "C" void kernel_launch(void* const* d_in, const int* in_sizes, int n_in,
                              void* d_out, int out_size, void* d_ws, size_t ws_size,
                              hipStream_t stream) {
    const void* ml   = d_in[0];
    const void* bbox = d_in[1];
    const void* WU   = d_in[2];
    const void* WV   = d_in[3];
    const void* Wpos = d_in[4];
    const void* WP   = d_in[5];
    const int*  cls  = (const int*)d_in[6];

    u16* relN = (u16*)d_ws;   // 32 KB, [n][m] row-major bf16

    // Host-side dtype dispatch: ml is 128*192*192 = 4,718,592 elements.
    // If in_sizes[0] is a byte count it uniquely identifies the dtype and we
    // can skip the wrong-variant dummy launches. Anything else -> baseline
    // dual-launch fallback (in-kernel detect picks the right path).
    const long long ML_ELEMS = 4718592LL;
    long long sz0 = (in_sizes && n_in > 0) ? (long long)in_sizes[0] : 0;

    if (sz0 == ML_ELEMS * 2) {          // bf16
        k_rel<1><<<dim3(128), dim3(128), 0, stream>>>(ml, bbox, WU, WV, Wpos, WP, cls, relN);
        k_main<1><<<dim3(256), dim3(256), 0, stream>>>(ml, relN, d_out);
    } else if (sz0 == ML_ELEMS * 4) {   // fp32
        k_rel<0><<<dim3(128), dim3(128), 0, stream>>>(ml, bbox, WU, WV, Wpos, WP, cls, relN);
        k_main<0><<<dim3(256), dim3(256), 0, stream>>>(ml, relN, d_out);
    } else {                            // unknown -> proven baseline behavior
        k_rel<1><<<dim3(128), dim3(128), 0, stream>>>(ml, bbox, WU, WV, Wpos, WP, cls, relN);
        k_rel<0><<<dim3(128), dim3(128), 0, stream>>>(ml, bbox, WU, WV, Wpos, WP, cls, relN);
        k_main<1><<<dim3(256), dim3(256), 0, stream>>>(ml, relN, d_out);
        k_main<0><<<dim3(256), dim3(256), 0, stream>>>(ml, relN, d_out);
    }
}